// Round 7
// baseline (357.620 us; speedup 1.0000x reference)
//
#include <hip/hip_runtime.h>
#include <stdint.h>

// SynapticSNN — all fp32. cur1 = X@W1^T + b1 (VALU GEMM, no fp32 MFMA on
// CDNA4), fused 100-step recurrence with EXACT np fp32 op order (no FMA
// contraction — a reset-decision flip changes mem by 1.0 and the final
// spike; one flip can add ~0.1 to an output element vs threshold 0.068).
// R7 structural change: GEMM2 (out = spk@W2^T + b2) is FUSED into k1's
// epilogue. Each block holds its 64x64 spike tile -> LDS, stages the W2
// slice [64k][128n] once, runs a 64-k FMA loop (32 acc/thread), and
// atomicAdds partials into out (pre-initialized to b2 by snn_init).
// Deletes k2/k3, the 16 MB spk HBM round-trip, and two launch gaps.
// R5/R6 established: recurrence state fits in VGPRs (no AGPR shuttles);
// k1 staging prefetch is neutral. k2+k3 cost 73-99 us for 14 us of FMA.

#define NSTEPS 100

// ---------------------------------------------------------------------------
// init: out[m][n] = b2[n]  (atomic accumulation target; d_out is re-poisoned
// to 0xAA before every timed launch, so this must run every call)
// ---------------------------------------------------------------------------
__global__ __launch_bounds__(256) void snn_init(
    const float* __restrict__ b2, float* __restrict__ out)
{
  const int idx = blockIdx.x * 256 + threadIdx.x;   // 131072 threads, 4 cols
  const int m = idx >> 5;
  const int c = (idx & 31) << 2;
  const float4 o = *(const float4*)(b2 + c);
  *(float4*)(out + (size_t)m * 128 + c) = o;
}

// ---------------------------------------------------------------------------
// Kernel 1: GEMM1 (64x64 tile, 4x4/thread, BK=32) + recurrence + fused GEMM2
// partial with atomicAdd epilogue.
// LDS plan (50176 B, phases separated by barriers):
//   phase 1 (GEMM1):  As = smem[0..2176), Bs = smem[2176..4352)  (floats)
//   phase 2 (GEMM2):  S_T = smem[0..4352)   [hid 64][m 64] stride 68
//                     W2s = smem[4352..12544) [k 64][n 128] stride 128
// ---------------------------------------------------------------------------
__global__ __launch_bounds__(256, 4) void snn_k1(
    const float* __restrict__ X, const float* __restrict__ W1,
    const float* __restrict__ b1, const float* __restrict__ betap,
    const float* __restrict__ W2, float* __restrict__ out)
{
  __shared__ __align__(16) float smem[12544];
  float* As  = smem;             // [k 32][m 64] stride 68
  float* Bs  = smem + 2176;      // [k 32][n 64] stride 68
  float* S_T = smem;             // [hid 64][m 64] stride 68
  float* W2s = smem + 4352;      // [k 64][n 128] stride 128

  const int tid = threadIdx.x;
  const int bm  = blockIdx.y * 64;   // batch rows
  const int bn  = blockIdx.x * 64;   // hidden cols
  const int ty  = tid >> 4;          // 0..15
  const int tx  = tid & 15;          // 0..15
  const int sc  = tid & 7;           // staging k-group (4 floats)
  const int sr  = tid >> 3;          // staging row 0..31

  float acc[4][4] = {};

  // ---------------- phase 1: GEMM1 ----------------
  for (int k0 = 0; k0 < 256; k0 += 32) {
    #pragma unroll
    for (int h = 0; h < 2; ++h) {
      const int r = sr + h * 32;
      const float4 xa = *(const float4*)(X  + (size_t)(bm + r) * 256 + k0 + sc * 4);
      const float4 wa = *(const float4*)(W1 + (size_t)(bn + r) * 256 + k0 + sc * 4);
      As[(sc * 4 + 0) * 68 + r] = xa.x;
      As[(sc * 4 + 1) * 68 + r] = xa.y;
      As[(sc * 4 + 2) * 68 + r] = xa.z;
      As[(sc * 4 + 3) * 68 + r] = xa.w;
      Bs[(sc * 4 + 0) * 68 + r] = wa.x;
      Bs[(sc * 4 + 1) * 68 + r] = wa.y;
      Bs[(sc * 4 + 2) * 68 + r] = wa.z;
      Bs[(sc * 4 + 3) * 68 + r] = wa.w;
    }
    __syncthreads();
    #pragma unroll
    for (int kk = 0; kk < 32; ++kk) {
      const float4 a4 = *(const float4*)(As + kk * 68 + ty * 4);
      const float4 b4 = *(const float4*)(Bs + kk * 68 + tx * 4);
      const float av[4] = {a4.x, a4.y, a4.z, a4.w};
      const float bv[4] = {b4.x, b4.y, b4.z, b4.w};
      #pragma unroll
      for (int i = 0; i < 4; ++i)
        #pragma unroll
        for (int j = 0; j < 4; ++j)
          acc[i][j] += av[i] * bv[j];
    }
    __syncthreads();
  }

  // ---------------- phase 2: recurrence (np fp32 semantics) ----------------
  float beta = betap[0];
  beta = fminf(fmaxf(beta, 0.0f), 1.0f);
  float bias[4];
  #pragma unroll
  for (int j = 0; j < 4; ++j) bias[j] = b1[bn + tx * 4 + j];

  float cc[16];
  #pragma unroll
  for (int i = 0; i < 4; ++i)
    #pragma unroll
    for (int j = 0; j < 4; ++j)
      cc[i * 4 + j] = acc[i][j] + bias[j];

  #pragma unroll
  for (int h = 0; h < 2; ++h) {          // half h: elements h*8 .. h*8+7
    float syn[8], mem[8];
    #pragma unroll
    for (int e = 0; e < 8; ++e) { syn[e] = 0.0f; mem[e] = 0.0f; }

    #pragma unroll 1
    for (int t = 0; t < NSTEPS; ++t) {
      #pragma unroll
      for (int e = 0; e < 8; ++e) {
        const float rst = (mem[e] > 1.0f) ? 1.0f : 0.0f;   // pre-update reset
        syn[e] = __fadd_rn(__fmul_rn(0.9f, syn[e]), cc[h * 8 + e]);
        mem[e] = __fsub_rn(__fadd_rn(__fmul_rn(beta, mem[e]), syn[e]), rst);
      }
    }

    // spikes -> S_T[hid][m] in LDS (safe: all As/Bs reads are behind the
    // final GEMM1 barrier)
    #pragma unroll
    for (int i = 0; i < 2; ++i) {
      const int m = ty * 4 + h * 2 + i;
      #pragma unroll
      for (int j = 0; j < 4; ++j)
        S_T[(tx * 4 + j) * 68 + m] = (mem[i * 4 + j] > 1.0f) ? 1.0f : 0.0f;
    }
  }

  // ---------------- phase 3: stage W2 slice, fused GEMM2 ----------------
  // W2s[k][n] = W2[n][bn + k]; u-sweep is coalesced (16 consecutive float4
  // per 16 lanes along one W2 row).
  #pragma unroll
  for (int it = 0; it < 8; ++it) {
    const int u  = it * 256 + tid;     // 0..2047
    const int n  = u >> 4;             // 0..127
    const int kq = u & 15;             // k = kq*4 .. +3
    const float4 w = *(const float4*)(W2 + (size_t)n * 2048 + bn + kq * 4);
    W2s[(kq * 4 + 0) * 128 + n] = w.x;
    W2s[(kq * 4 + 1) * 128 + n] = w.y;
    W2s[(kq * 4 + 2) * 128 + n] = w.z;
    W2s[(kq * 4 + 3) * 128 + n] = w.w;
  }
  __syncthreads();

  // each thread: 4 m-rows (ty*4..+3) x 8 n-cols (tx*4..+3 and 64+tx*4..+3)
  float a2[4][8] = {};
  #pragma unroll 2
  for (int k = 0; k < 64; ++k) {
    const float4 s4 = *(const float4*)(S_T + k * 68 + ty * 4);
    const float4 wA = *(const float4*)(W2s + k * 128 + tx * 4);
    const float4 wB = *(const float4*)(W2s + k * 128 + 64 + tx * 4);
    const float sv[4] = {s4.x, s4.y, s4.z, s4.w};
    const float wa[4] = {wA.x, wA.y, wA.z, wA.w};
    const float wb[4] = {wB.x, wB.y, wB.z, wB.w};
    #pragma unroll
    for (int i = 0; i < 4; ++i) {
      #pragma unroll
      for (int j = 0; j < 4; ++j) {
        a2[i][j]     += sv[i] * wa[j];
        a2[i][4 + j] += sv[i] * wb[j];
      }
    }
  }

  #pragma unroll
  for (int i = 0; i < 4; ++i) {
    float* rowp = out + (size_t)(bm + ty * 4 + i) * 128;
    #pragma unroll
    for (int j = 0; j < 4; ++j) {
      atomicAdd(rowp + tx * 4 + j,      a2[i][j]);
      atomicAdd(rowp + 64 + tx * 4 + j, a2[i][4 + j]);
    }
  }
}

extern "C" void kernel_launch(void* const* d_in, const int* in_sizes, int n_in,
                              void* d_out, int out_size, void* d_ws, size_t ws_size,
                              hipStream_t stream) {
  const float* X    = (const float*)d_in[0];  // [4096,256]
  const float* W1   = (const float*)d_in[1];  // [2048,256]
  const float* b1   = (const float*)d_in[2];  // [2048]
  const float* W2   = (const float*)d_in[3];  // [128,2048]
  const float* b2   = (const float*)d_in[4];  // [128]
  const float* beta = (const float*)d_in[5];  // scalar
  float* out = (float*)d_out;                 // [4096,128] fp32

  snn_init<<<512, 256, 0, stream>>>(b2, out);
  snn_k1<<<dim3(32, 64), 256, 0, stream>>>(X, W1, b1, beta, W2, out);
}

// Round 8
// 214.992 us; speedup vs baseline: 1.6634x; 1.6634x over previous
//
#include <hip/hip_runtime.h>
#include <stdint.h>

// SynapticSNN — fp32 problem. cur1 = X@W1^T + b1 must be fp32 (bf16 error on
// cur1 amplifies ~67x through the 100-step recurrence -> spike flips; one
// final-spike flip can add ~0.1 to an output vs threshold 0.068). Recurrence
// uses EXACT np fp32 op order (no FMA contraction). GEMM2 (out = spk@W2^T+b2)
// is NOT error-amplified (final op): spikes {0,1} are exact in bf16 and
// bf16(W2) adds only ~1e-3 -> k2 uses 16x16x32 bf16 MFMA.
// R7 post-mortem: fused atomicAdd epilogue caused 256 MB HBM atomic RMW
// traffic (non-coherent per-XCD L2s) + occupancy loss -> reverted.
// R5/R6 established: k1 is ~50 us above its 105 us VALU floor and immune to
// staging prefetch tweaks; k1 frozen here while the tail is collapsed.

typedef __attribute__((ext_vector_type(8))) short short8;
typedef __attribute__((ext_vector_type(4))) float floatx4;

#define NSTEPS 100

static __device__ __forceinline__ uint32_t f2bf2(float lo, float hi) {
  union { float f; uint32_t u; } a, b; a.f = lo; b.f = hi;
  uint32_t x = (a.u + 0x7FFFu + ((a.u >> 16) & 1u)) >> 16;
  uint32_t y = (b.u + 0x7FFFu + ((b.u >> 16) & 1u)) & 0xFFFF0000u;
  return x | y;
}

// ---------------------------------------------------------------------------
// Kernel 1 (frozen R6 form): GEMM1 64x64 tile 4x4/thread BK=32 + recurrence.
// spk (bf16 {0,1}) [4096,2048] -> ws.
// ---------------------------------------------------------------------------
__global__ __launch_bounds__(256, 4) void snn_k1(
    const float* __restrict__ X, const float* __restrict__ W1,
    const float* __restrict__ b1, const float* __restrict__ betap,
    uint16_t* __restrict__ spk)
{
  __shared__ __align__(16) float As[32 * 68];
  __shared__ __align__(16) float Bs[32 * 68];
  const int tid = threadIdx.x;
  const int bm  = blockIdx.y * 64;   // batch rows
  const int bn  = blockIdx.x * 64;   // hidden cols
  const int ty  = tid >> 4;          // 0..15
  const int tx  = tid & 15;          // 0..15
  const int sc  = tid & 7;           // staging k-group (4 floats)
  const int sr  = tid >> 3;          // staging row 0..31

  float acc[4][4] = {};

  float4 xa[2], wa[2];
  #pragma unroll
  for (int h = 0; h < 2; ++h) {
    const int r = sr + h * 32;
    xa[h] = *(const float4*)(X  + (size_t)(bm + r) * 256 + sc * 4);
    wa[h] = *(const float4*)(W1 + (size_t)(bn + r) * 256 + sc * 4);
  }

  #pragma unroll 1
  for (int k0 = 0; k0 < 256; k0 += 32) {
    #pragma unroll
    for (int h = 0; h < 2; ++h) {
      const int r = sr + h * 32;
      As[(sc * 4 + 0) * 68 + r] = xa[h].x;
      As[(sc * 4 + 1) * 68 + r] = xa[h].y;
      As[(sc * 4 + 2) * 68 + r] = xa[h].z;
      As[(sc * 4 + 3) * 68 + r] = xa[h].w;
      Bs[(sc * 4 + 0) * 68 + r] = wa[h].x;
      Bs[(sc * 4 + 1) * 68 + r] = wa[h].y;
      Bs[(sc * 4 + 2) * 68 + r] = wa[h].z;
      Bs[(sc * 4 + 3) * 68 + r] = wa[h].w;
    }
    __syncthreads();

    if (k0 < 224) {
      const int kn = k0 + 32;
      #pragma unroll
      for (int h = 0; h < 2; ++h) {
        const int r = sr + h * 32;
        xa[h] = *(const float4*)(X  + (size_t)(bm + r) * 256 + kn + sc * 4);
        wa[h] = *(const float4*)(W1 + (size_t)(bn + r) * 256 + kn + sc * 4);
      }
    }

    #pragma unroll
    for (int kk = 0; kk < 32; ++kk) {
      const float4 a4 = *(const float4*)(As + kk * 68 + ty * 4);
      const float4 b4 = *(const float4*)(Bs + kk * 68 + tx * 4);
      const float av[4] = {a4.x, a4.y, a4.z, a4.w};
      const float bv[4] = {b4.x, b4.y, b4.z, b4.w};
      #pragma unroll
      for (int i = 0; i < 4; ++i)
        #pragma unroll
        for (int j = 0; j < 4; ++j)
          acc[i][j] += av[i] * bv[j];
    }
    __syncthreads();
  }

  float beta = betap[0];
  beta = fminf(fmaxf(beta, 0.0f), 1.0f);
  float bias[4];
  #pragma unroll
  for (int j = 0; j < 4; ++j) bias[j] = b1[bn + tx * 4 + j];

  float cc[16];
  #pragma unroll
  for (int i = 0; i < 4; ++i)
    #pragma unroll
    for (int j = 0; j < 4; ++j)
      cc[i * 4 + j] = acc[i][j] + bias[j];

  #pragma unroll
  for (int h = 0; h < 2; ++h) {
    float syn[8], mem[8];
    #pragma unroll
    for (int e = 0; e < 8; ++e) { syn[e] = 0.0f; mem[e] = 0.0f; }

    #pragma unroll 1
    for (int t = 0; t < NSTEPS; ++t) {
      #pragma unroll
      for (int e = 0; e < 8; ++e) {
        const float rst = (mem[e] > 1.0f) ? 1.0f : 0.0f;   // pre-update reset
        syn[e] = __fadd_rn(__fmul_rn(0.9f, syn[e]), cc[h * 8 + e]);
        mem[e] = __fsub_rn(__fadd_rn(__fmul_rn(beta, mem[e]), syn[e]), rst);
      }
    }

    #pragma unroll
    for (int i = 0; i < 2; ++i) {
      ushort4 o;
      o.x = (mem[i * 4 + 0] > 1.0f) ? (uint16_t)0x3F80u : (uint16_t)0u;
      o.y = (mem[i * 4 + 1] > 1.0f) ? (uint16_t)0x3F80u : (uint16_t)0u;
      o.z = (mem[i * 4 + 2] > 1.0f) ? (uint16_t)0x3F80u : (uint16_t)0u;
      o.w = (mem[i * 4 + 3] > 1.0f) ? (uint16_t)0x3F80u : (uint16_t)0u;
      *(ushort4*)(spk + (size_t)(bm + ty * 4 + h * 2 + i) * 2048 + bn + tx * 4) = o;
    }
  }
}

// ---------------------------------------------------------------------------
// Kernel 2: spk[4096,2048](bf16) @ W2[128,2048]^T via 16x16x32 bf16 MFMA.
// 128m x 128n tiles, split-K=8 (K-chunk 256, BK=64). Grid (32, 8).
// W2 fp32 -> bf16 (rne) in-register during staging. Padded LDS stride 72
// shorts (2-way-only bank aliasing = free). part[kc][4096][128] fp32 -> ws.
// Fragment layout (verified m89/m91/m92): A/B [m=lane&15][k=quad*8+j];
// C/D col=lane&15, row=quad*4+reg.
// ---------------------------------------------------------------------------
#define PS 72

__global__ __launch_bounds__(256) void snn_k2(
    const uint16_t* __restrict__ spk, const float* __restrict__ W2,
    float* __restrict__ part)
{
  __shared__ short As[128 * PS];
  __shared__ short Bs[128 * PS];
  const int tid  = threadIdx.x;
  const int lane = tid & 63;
  const int w    = tid >> 6;
  const int wm   = (w >> 1) * 64;
  const int wn   = (w & 1) * 64;
  const int bm   = blockIdx.x * 128;
  const int kc   = blockIdx.y;          // K chunk of 256

  floatx4 acc[4][4] = {};

  #pragma unroll 1
  for (int kk = 0; kk < 4; ++kk) {
    const int k0 = kc * 256 + kk * 64;
    // stage A: spk bf16, 16B/unit
    #pragma unroll
    for (int p = 0; p < 4; ++p) {
      const int u = p * 256 + tid;
      const int r = u >> 3, c = u & 7;
      const int4 va = *(const int4*)(spk + (size_t)(bm + r) * 2048 + k0 + c * 8);
      *(int4*)(As + r * PS + c * 8) = va;
    }
    // stage B: W2 fp32 -> bf16 pack, 8 floats/unit
    #pragma unroll
    for (int p = 0; p < 4; ++p) {
      const int u = p * 256 + tid;
      const int n = u >> 3, c = u & 7;
      const float* wp = W2 + (size_t)n * 2048 + k0 + c * 8;
      const float4 w0 = *(const float4*)(wp);
      const float4 w1 = *(const float4*)(wp + 4);
      int4 pk;
      pk.x = (int)f2bf2(w0.x, w0.y);
      pk.y = (int)f2bf2(w0.z, w0.w);
      pk.z = (int)f2bf2(w1.x, w1.y);
      pk.w = (int)f2bf2(w1.z, w1.w);
      *(int4*)(Bs + n * PS + c * 8) = pk;
    }
    __syncthreads();

    #pragma unroll
    for (int ks = 0; ks < 2; ++ks) {
      const int kb = ks * 4 + (lane >> 4);   // k-chunk 0..7
      const int fe = lane & 15;
      short8 a8[4], b8[4];
      #pragma unroll
      for (int tm = 0; tm < 4; ++tm)
        a8[tm] = *(const short8*)(As + (wm + tm * 16 + fe) * PS + kb * 8);
      #pragma unroll
      for (int tn = 0; tn < 4; ++tn)
        b8[tn] = *(const short8*)(Bs + (wn + tn * 16 + fe) * PS + kb * 8);
      #pragma unroll
      for (int tm = 0; tm < 4; ++tm)
        #pragma unroll
        for (int tn = 0; tn < 4; ++tn)
          acc[tm][tn] = __builtin_amdgcn_mfma_f32_16x16x32_bf16(
              a8[tm], b8[tn], acc[tm][tn], 0, 0, 0);
    }
    __syncthreads();
  }

  const int fe = lane & 15;
  const int fr = (lane >> 4) * 4;   // C/D: col=lane&15, row=quad*4+reg
  #pragma unroll
  for (int tm = 0; tm < 4; ++tm)
    #pragma unroll
    for (int tn = 0; tn < 4; ++tn)
      #pragma unroll
      for (int r = 0; r < 4; ++r) {
        const int row = bm + wm + tm * 16 + fr + r;
        const int col = wn + tn * 16 + fe;
        part[((size_t)kc * 4096 + row) * 128 + col] = acc[tm][tn][r];
      }
}

// ---------------------------------------------------------------------------
// Kernel 3: out[m][n] = sum_kc part[kc][m][n] + b2[n]  (fp32 out)
// ---------------------------------------------------------------------------
__global__ __launch_bounds__(256) void snn_k3(
    const float* __restrict__ part, const float* __restrict__ b2,
    float* __restrict__ out)
{
  const int idx = blockIdx.x * 256 + threadIdx.x;
  const int m = idx >> 5;
  const int c = (idx & 31) << 2;
  float s0 = 0.f, s1 = 0.f, s2 = 0.f, s3 = 0.f;
  #pragma unroll
  for (int kc = 0; kc < 8; ++kc) {
    const float4 p = *(const float4*)(part + ((size_t)kc * 4096 + m) * 128 + c);
    s0 += p.x; s1 += p.y; s2 += p.z; s3 += p.w;
  }
  float4 o;
  o.x = s0 + b2[c + 0];
  o.y = s1 + b2[c + 1];
  o.z = s2 + b2[c + 2];
  o.w = s3 + b2[c + 3];
  *(float4*)(out + (size_t)m * 128 + c) = o;
}

extern "C" void kernel_launch(void* const* d_in, const int* in_sizes, int n_in,
                              void* d_out, int out_size, void* d_ws, size_t ws_size,
                              hipStream_t stream) {
  const float* X    = (const float*)d_in[0];  // [4096,256]
  const float* W1   = (const float*)d_in[1];  // [2048,256]
  const float* b1   = (const float*)d_in[2];  // [2048]
  const float* W2   = (const float*)d_in[3];  // [128,2048]
  const float* b2   = (const float*)d_in[4];  // [128]
  const float* beta = (const float*)d_in[5];  // scalar
  float* out = (float*)d_out;                 // [4096,128] fp32

  uint16_t* spk = (uint16_t*)d_ws;                               // 16 MiB
  float* part = (float*)((char*)d_ws + (size_t)4096 * 2048 * 2); // 16 MiB

  snn_k1<<<dim3(32, 64), 256, 0, stream>>>(X, W1, b1, beta, spk);
  snn_k2<<<dim3(32, 8), 256, 0, stream>>>(spk, W2, part);
  snn_k3<<<512, 256, 0, stream>>>(part, b2, out);
}